// Round 8
// baseline (52.839 us; speedup 1.0000x reference)
//
#include <hip/hip_runtime.h>
#include <hip/hip_bf16.h>

// GNNLayer: per-edge MLP score -> sampled segment-sum -> fc2 + BatchNorm.
// Algebra: sum(h@w2.T+b2, axis=1) == h . colsum(w2) + sum(b2); only the first
// min(64, group_len) edges per (sorted) head contribute.
// R4: cooperative grid.sync costs +27us under graph replay -> plain kernels.
// R6: splitting edge into score+gather cost +9.4us -> monolithic edge kept.
// R7 analysis: edge grid is fully co-resident; the limiter is the tail-gather
// phase's random-access bytes (64MB of 512B rows from a 25.6MB table).
// R8: tail_emb -> bf16 in prep; edge gathers 256B rows (half the bytes).

#define D 128

typedef __attribute__((ext_vector_type(8))) short bf16x8;
typedef __attribute__((ext_vector_type(8))) unsigned short u16x8;
typedef __attribute__((ext_vector_type(4))) float f32x4;
typedef __attribute__((ext_vector_type(4))) unsigned short u16x4;

__device__ __forceinline__ unsigned short f2bf(float f) {
  union { float f; unsigned int u; } v; v.f = f;
  unsigned int r = v.u + 0x7FFFu + ((v.u >> 16) & 1u);
  return (unsigned short)(r >> 16);
}
__device__ __forceinline__ float bf2f(unsigned short h) {
  union { unsigned int u; float f; } v; v.u = ((unsigned int)h) << 16;
  return v.f;
}

// ---- prep: starts[] scatter, bf16 conversions (incl. tail_emb), w2 colsum,
// ---- b2 sum, x-copy ----
__global__ void prep_kernel(const float* __restrict__ w1,
                            const float* __restrict__ w2,
                            const float* __restrict__ b2,
                            const float* __restrict__ drug_emb,
                            const float* __restrict__ fc2_w,
                            const float* __restrict__ x,
                            const float* __restrict__ tail_emb,
                            const int* __restrict__ head,
                            unsigned short* __restrict__ w1b,
                            unsigned short* __restrict__ drugb,
                            unsigned short* __restrict__ fc2wb,
                            unsigned short* __restrict__ tailb,
                            int* __restrict__ starts,
                            float* __restrict__ w2s,
                            float* __restrict__ b2sum,
                            float* __restrict__ out_hi,
                            int E_total, int n_drug, int total, int n_tail_elems,
                            int gridsz) {
  int g = blockIdx.x * 256 + threadIdx.x;
  if (g < E_total) {
    int h1 = head[g];
    int h0 = (g == 0) ? -1 : head[g - 1];
    for (int d = h0 + 1; d <= h1; ++d) starts[d] = g;   // usually 0 iters
    if (g == E_total - 1) {
      for (int d = h1 + 1; d <= n_drug; ++d) starts[d] = E_total;
    }
  }
  if (g < D * D) w1b[g] = f2bf(w1[g]);
  if (g < 2 * D * D) fc2wb[g] = f2bf(fc2_w[g]);
  if (g < n_drug * D) drugb[g] = f2bf(drug_emb[g]);
  if (g < total) out_hi[g] = x[g];
  // tail_emb -> bf16: grid-stride, 4 elems/thread/iter (f32x4 -> u16x4)
  {
    const int nthreads = gridsz * 256;
    const int n4 = n_tail_elems >> 2;
    for (int i = g; i < n4; i += nthreads) {
      f32x4 v = ((const f32x4*)tail_emb)[i];
      u16x4 pk = { f2bf(v.x), f2bf(v.y), f2bf(v.z), f2bf(v.w) };
      ((u16x4*)tailb)[i] = pk;
    }
  }
  // w2 colsum: 8 independent partial accumulators -> loads fully pipelined
  if (g < D) {
    float s0=0.f,s1=0.f,s2=0.f,s3=0.f,s4=0.f,s5=0.f,s6=0.f,s7=0.f;
    #pragma unroll
    for (int j = 0; j < D; j += 8) {
      s0 += w2[(j+0)*D+g]; s1 += w2[(j+1)*D+g];
      s2 += w2[(j+2)*D+g]; s3 += w2[(j+3)*D+g];
      s4 += w2[(j+4)*D+g]; s5 += w2[(j+5)*D+g];
      s6 += w2[(j+6)*D+g]; s7 += w2[(j+7)*D+g];
    }
    w2s[g] = ((s0+s1)+(s2+s3))+((s4+s5)+(s6+s7));
  }
  // b2 sum: wave 0 of block 0, parallel shuffle reduce
  if (g < 64) {
    float v = b2[g] + b2[g + 64];
    v += __shfl_xor(v, 1);  v += __shfl_xor(v, 2);  v += __shfl_xor(v, 4);
    v += __shfl_xor(v, 8);  v += __shfl_xor(v, 16); v += __shfl_xor(v, 32);
    if (g == 0) b2sum[0] = v;
  }
}

// ---- per-drug: had = drug*rel -> z = had@w1^T + b1 (bf16 MFMA) -> sigmoid
// ---- -> score = h.w2s + b2sum -> neigh = sum score*tail (bf16 in/out) ----
__global__ __launch_bounds__(256, 2) void edge_kernel(
    const float* __restrict__ drug_emb, const float* __restrict__ rel_emb,
    const unsigned short* __restrict__ tailb, const float* __restrict__ b1,
    const int* __restrict__ dkg_rel, const int* __restrict__ dkg_tail,
    const int* __restrict__ starts, const unsigned short* __restrict__ w1b,
    const float* __restrict__ w2s, const float* __restrict__ b2sum,
    const int* __restrict__ samp, unsigned short* __restrict__ neighb) {
  const int n = blockIdx.x;
  const int tid = threadIdx.x;
  const int w = tid >> 6, lane = tid & 63;
  const int fl = lane & 15, kh = lane >> 4;
  const int g = tid >> 5, l5 = tid & 31;   // 8 groups x 32 lanes

  __shared__ __align__(16) unsigned short hadb[64][136];  // 272B row: 2-way alias only
  __shared__ float scorePart[4][64];
  __shared__ float scoreL[64];
  __shared__ int   tails[64];
  __shared__ int   relIdx[64];
  float* gpart = (float*)&hadb[0][0];  // alias: gather partials (4KB), reused after MFMA phase

  const int base = starts[n];
  const int end  = starts[n + 1];
  int ss = samp[0]; if (ss > 64) ss = 64;
  int cnt = end - base; if (cnt > ss) cnt = ss; if (cnt < 0) cnt = 0;

  if (tid < 64) {
    tails[tid]  = (tid < cnt) ? dkg_tail[base + tid] : 0;
    relIdx[tid] = (tid < cnt) ? dkg_rel[base + tid] : 0;
  }

  const f32x4 dr = *(const f32x4*)(drug_emb + (long)n * D + l5 * 4);

  // B fragments: wave w covers feature tiles {2w, 2w+1}
  bf16x8 bfr[2][4];
  float w2sr[2], b1r[2];
  #pragma unroll
  for (int jq = 0; jq < 2; ++jq) {
    int f = (w * 2 + jq) * 16 + fl;
    w2sr[jq] = w2s[f];
    b1r[jq]  = b1[f];
    #pragma unroll
    for (int kt = 0; kt < 4; ++kt)
      bfr[jq][kt] = *(const bf16x8*)(w1b + f * D + kt * 32 + kh * 8);
  }
  const float b2s = b2sum[0];

  __syncthreads();  // relIdx/tails ready

  // stage had (bf16): group g handles edges it*8+g; 32 lanes cover 128 feats
  #pragma unroll
  for (int it = 0; it < 8; ++it) {
    int e = it * 8 + g;
    int r = relIdx[e];
    f32x4 rl = *(const f32x4*)(rel_emb + (long)r * D + l5 * 4);
    f32x4 v = dr * rl;
    u16x4 pk = { f2bf(v.x), f2bf(v.y), f2bf(v.z), f2bf(v.w) };
    *(u16x4*)&hadb[e][l5 * 4] = pk;
  }

  // T14: issue bf16 tail-row loads now (8B/lane); consumed after score barrier.
  u16x4 trow[8];
  #pragma unroll
  for (int it = 0; it < 8; ++it) {
    int e = it * 8 + g;
    trow[it] = *(const u16x4*)(tailb + (long)tails[e] * D + l5 * 4);
  }

  __syncthreads();  // hadb ready

  f32x4 acc[4][2];
  #pragma unroll
  for (int mt = 0; mt < 4; ++mt)
    #pragma unroll
    for (int jq = 0; jq < 2; ++jq)
      acc[mt][jq] = (f32x4){b1r[jq], b1r[jq], b1r[jq], b1r[jq]};

  #pragma unroll
  for (int kt = 0; kt < 4; ++kt) {
    bf16x8 af[4];
    #pragma unroll
    for (int mt = 0; mt < 4; ++mt)
      af[mt] = *(const bf16x8*)&hadb[mt * 16 + fl][kt * 32 + kh * 8];
    #pragma unroll
    for (int mt = 0; mt < 4; ++mt)
      #pragma unroll
      for (int jq = 0; jq < 2; ++jq)
        acc[mt][jq] = __builtin_amdgcn_mfma_f32_16x16x32_bf16(af[mt], bfr[jq][kt], acc[mt][jq], 0, 0, 0);
  }

  // epilogue: sigmoid, partial score over this wave's 32 features, 16-lane reduce
  #pragma unroll
  for (int mt = 0; mt < 4; ++mt) {
    #pragma unroll
    for (int r = 0; r < 4; ++r) {
      float p = 0.f;
      #pragma unroll
      for (int jq = 0; jq < 2; ++jq) {
        float hh = 1.f / (1.f + __expf(-acc[mt][jq][r]));
        p += hh * w2sr[jq];
      }
      p += __shfl_xor(p, 1);
      p += __shfl_xor(p, 2);
      p += __shfl_xor(p, 4);
      p += __shfl_xor(p, 8);
      if (fl == 0) scorePart[w][mt * 16 + kh * 4 + r] = p;
    }
  }
  __syncthreads();

  if (tid < 64) {
    float sc = scorePart[0][tid] + scorePart[1][tid] + scorePart[2][tid] + scorePart[3][tid] + b2s;
    scoreL[tid] = (tid < cnt) ? sc : 0.f;
  }
  __syncthreads();

  // weighted accumulate of prefetched bf16 tail rows
  f32x4 a = (f32x4){0.f, 0.f, 0.f, 0.f};
  #pragma unroll
  for (int it = 0; it < 8; ++it) {
    int e = it * 8 + g;
    float s = scoreL[e];            // 0 for e >= cnt
    a.x += bf2f(trow[it].x) * s;
    a.y += bf2f(trow[it].y) * s;
    a.z += bf2f(trow[it].z) * s;
    a.w += bf2f(trow[it].w) * s;
  }
  ((f32x4*)gpart)[g * 32 + l5] = a;
  __syncthreads();

  if (tid < D) {
    float s = 0.f;
    #pragma unroll
    for (int q = 0; q < 8; ++q) s += gpart[q * 128 + tid];
    neighb[(long)n * D + tid] = f2bf(s);
  }
}

// ---- fc2 via bf16 MFMA + fused BN partial stats: 64 rows/block ----
__global__ __launch_bounds__(256, 1) void fc2s_kernel(
    const unsigned short* __restrict__ drugb, const unsigned short* __restrict__ neighb,
    const unsigned short* __restrict__ fc2wb, const float* __restrict__ fc2_b,
    float* __restrict__ out_pre, float* __restrict__ partial, int n_drug) {
  const int tid = threadIdx.x;
  const int w = tid >> 6, lane = tid & 63;
  const int fl = lane & 15, kh = lane >> 4;
  const int n0 = blockIdx.x * 64;

  __shared__ __align__(16) unsigned short asmem[64][264];  // 528B row stride: 2-way alias only

  #pragma unroll
  for (int it = 0; it < 8; ++it) {
    int c = it * 256 + tid;
    int row = c >> 5;
    int off = (c & 31) * 16;
    int gr = n0 + row;
    u16x8 v = (u16x8){0,0,0,0,0,0,0,0};
    if (gr < n_drug) {
      const unsigned short* src = (off < 256) ? (drugb + (long)gr * D + (off >> 1))
                                              : (neighb + (long)gr * D + ((off - 256) >> 1));
      v = *(const u16x8*)src;
    }
    *(u16x8*)((char*)&asmem[0][0] + row * 528 + off) = v;
  }

  bf16x8 bfr[2][8];
  float bjr[2];
  #pragma unroll
  for (int jq = 0; jq < 2; ++jq) {
    int f = (w * 2 + jq) * 16 + fl;
    bjr[jq] = fc2_b[f];
    #pragma unroll
    for (int kt = 0; kt < 8; ++kt)
      bfr[jq][kt] = *(const bf16x8*)(fc2wb + (long)f * 256 + kt * 32 + kh * 8);
  }
  __syncthreads();

  f32x4 acc[4][2];
  #pragma unroll
  for (int mt = 0; mt < 4; ++mt)
    #pragma unroll
    for (int jq = 0; jq < 2; ++jq)
      acc[mt][jq] = (f32x4){bjr[jq], bjr[jq], bjr[jq], bjr[jq]};

  #pragma unroll
  for (int kt = 0; kt < 8; ++kt) {
    bf16x8 af[4];
    #pragma unroll
    for (int mt = 0; mt < 4; ++mt)
      af[mt] = *(const bf16x8*)((char*)&asmem[0][0] + (mt * 16 + fl) * 528 + kt * 64 + kh * 16);
    #pragma unroll
    for (int mt = 0; mt < 4; ++mt)
      #pragma unroll
      for (int jq = 0; jq < 2; ++jq)
        acc[mt][jq] = __builtin_amdgcn_mfma_f32_16x16x32_bf16(af[mt], bfr[jq][kt], acc[mt][jq], 0, 0, 0);
  }

  #pragma unroll
  for (int jq = 0; jq < 2; ++jq) {
    int j = (w * 2 + jq) * 16 + fl;
    float s = 0.f, s2 = 0.f;
    #pragma unroll
    for (int mt = 0; mt < 4; ++mt) {
      #pragma unroll
      for (int r = 0; r < 4; ++r) {
        int grow = n0 + mt * 16 + kh * 4 + r;
        float v = acc[mt][jq][r];
        if (grow < n_drug) {
          out_pre[(long)grow * D + j] = v;
          s += v; s2 += v * v;
        }
      }
    }
    s  += __shfl_xor(s, 16);  s  += __shfl_xor(s, 32);
    s2 += __shfl_xor(s2, 16); s2 += __shfl_xor(s2, 32);
    if (kh == 0)
      ((float2*)partial)[(long)blockIdx.x * D + j] = make_float2(s, s2);
  }
}

// ---- fused BN final reduce + normalize: 8 rows/block ----
__global__ void bnfin_kernel(const float* __restrict__ out_pre,
                             const float* __restrict__ partial,
                             const float* __restrict__ gamma,
                             const float* __restrict__ beta,
                             float* __restrict__ out,
                             int n_drug, int nblocks) {
  const int tid = threadIdx.x;
  const int j = tid & 127, h = tid >> 7;
  const int n0 = blockIdx.x * 8 + h * 4;

  float v[4];
  #pragma unroll
  for (int r = 0; r < 4; ++r)
    v[r] = out_pre[(long)(n0 + r) * D + j];

  float s = 0.f, s2 = 0.f;
  for (int b = 0; b < nblocks; ++b) {
    float2 p = ((const float2*)partial)[(long)b * D + j];
    s += p.x; s2 += p.y;
  }
  float mean = s / (float)n_drug;
  float var  = s2 / (float)n_drug - mean * mean;
  float inv  = rsqrtf(var + 1e-5f);
  float sc   = inv * gamma[j];
  float sh   = beta[j] - mean * sc;

  #pragma unroll
  for (int r = 0; r < 4; ++r)
    out[(long)(n0 + r) * D + j] = v[r] * sc + sh;
}

extern "C" void kernel_launch(void* const* d_in, const int* in_sizes, int n_in,
                              void* d_out, int out_size, void* d_ws, size_t ws_size,
                              hipStream_t stream) {
  const float* drug_emb = (const float*)d_in[0];
  const float* rel_emb  = (const float*)d_in[1];
  const float* tail_emb = (const float*)d_in[2];
  const float* w1       = (const float*)d_in[3];
  const float* b1       = (const float*)d_in[4];
  const float* w2       = (const float*)d_in[5];
  const float* b2       = (const float*)d_in[6];
  const float* fc2_w    = (const float*)d_in[7];
  const float* fc2_b    = (const float*)d_in[8];
  const float* gamma    = (const float*)d_in[9];
  const float* beta     = (const float*)d_in[10];
  const float* x        = (const float*)d_in[11];
  const int*   dkg_head = (const int*)d_in[12];
  const int*   dkg_rel  = (const int*)d_in[13];
  const int*   dkg_tail = (const int*)d_in[14];
  const int*   samp     = (const int*)d_in[15];

  const int n_drug = in_sizes[0] / D;   // 2000
  const int n_tail = in_sizes[2];       // 50000*128 elems
  const int E      = in_sizes[12];      // 500000
  float* out = (float*)d_out;
  const int total = out_size / 2;       // 256000

  // workspace layout
  char* ws = (char*)d_ws;
  int*            starts  = (int*)(ws + 0);                     // 8004 B
  unsigned short* w1b     = (unsigned short*)(ws + 8192);       // 32768 B
  float*          w2s     = (float*)(ws + 40960);               // 512 B
  float*          b2sum   = (float*)(ws + 41472);               // 4 B
  unsigned short* fc2wb   = (unsigned short*)(ws + 49152);      // 65536 B
  unsigned short* drugb   = (unsigned short*)(ws + 131072);     // 512000 B
  unsigned short* neighb  = (unsigned short*)(ws + 655360);     // 512000 B
  float*          out_pre = (float*)(ws + 1179648);             // 1024000 B
  float*          partial = (float*)(ws + 2228224);             // 32768 B
  unsigned short* tailb   = (unsigned short*)(ws + 2265088);    // 12,800,000 B

  const int nbf = (n_drug + 63) / 64;   // 32 fc2s blocks
  const int npre = (E + 256) / 256;     // 1954 prep blocks

  hipLaunchKernelGGL(prep_kernel, dim3(npre), dim3(256), 0, stream,
                     w1, w2, b2, drug_emb, fc2_w, x, tail_emb, dkg_head,
                     w1b, drugb, fc2wb, tailb, starts, w2s, b2sum, out + total,
                     E, n_drug, total, n_tail, npre);
  hipLaunchKernelGGL(edge_kernel, dim3(n_drug), dim3(256), 0, stream,
                     drug_emb, rel_emb, tailb, b1, dkg_rel, dkg_tail,
                     starts, w1b, w2s, b2sum, samp, neighb);
  hipLaunchKernelGGL(fc2s_kernel, dim3(nbf), dim3(256), 0, stream,
                     drugb, neighb, fc2wb, fc2_b, out_pre, partial, n_drug);
  hipLaunchKernelGGL(bnfin_kernel, dim3(n_drug / 8), dim3(256), 0, stream,
                     out_pre, partial, gamma, beta, out, n_drug, nbf);
}

// Round 9
// 41.676 us; speedup vs baseline: 1.2678x; 1.2678x over previous
//
#include <hip/hip_runtime.h>
#include <hip/hip_bf16.h>

// GNNLayer: per-edge MLP score -> sampled segment-sum -> fc2 + BatchNorm.
// Algebra: sum(h@w2.T+b2, axis=1) == h . colsum(w2) + sum(b2); only the first
// min(64, group_len) edges per (sorted) head contribute.
// R4: hipLaunchCooperativeKernel costs +27us under graph replay.
// R6: +1 kernel launch == +9.4us -> dispatch count dominates (~8-10us each).
// R8: halving gather bytes HURT (+3.4us prep work) -> gather not BW-bound.
// R9: 4 -> 3 kernels: fc2+BN fused via atomic-spin barrier (32 co-resident
// blocks, plain launch), BN stats via device-scope atomicAdd (XCD-coherent).

#define D 128

typedef __attribute__((ext_vector_type(8))) short bf16x8;
typedef __attribute__((ext_vector_type(8))) unsigned short u16x8;
typedef __attribute__((ext_vector_type(4))) float f32x4;
typedef __attribute__((ext_vector_type(4))) unsigned short u16x4;

__device__ __forceinline__ unsigned short f2bf(float f) {
  union { float f; unsigned int u; } v; v.f = f;
  unsigned int r = v.u + 0x7FFFu + ((v.u >> 16) & 1u);
  return (unsigned short)(r >> 16);
}

// ---- prep: starts[] scatter, bf16 conversions, w2 colsum, b2 sum, x-copy,
// ---- zero BN accumulators + spin counter (ws not re-poisoned between replays) ----
__global__ void prep_kernel(const float* __restrict__ w1,
                            const float* __restrict__ w2,
                            const float* __restrict__ b2,
                            const float* __restrict__ drug_emb,
                            const float* __restrict__ fc2_w,
                            const float* __restrict__ x,
                            const int* __restrict__ head,
                            unsigned short* __restrict__ w1b,
                            unsigned short* __restrict__ drugb,
                            unsigned short* __restrict__ fc2wb,
                            int* __restrict__ starts,
                            float* __restrict__ w2s,
                            float* __restrict__ b2sum,
                            float* __restrict__ out_hi,
                            float* __restrict__ bnacc,
                            int* __restrict__ counter,
                            int E_total, int n_drug, int total) {
  int g = blockIdx.x * 256 + threadIdx.x;
  if (g < E_total) {
    int h1 = head[g];
    int h0 = (g == 0) ? -1 : head[g - 1];
    for (int d = h0 + 1; d <= h1; ++d) starts[d] = g;   // usually 0 iters
    if (g == E_total - 1) {
      for (int d = h1 + 1; d <= n_drug; ++d) starts[d] = E_total;
    }
  }
  if (g < D * D) w1b[g] = f2bf(w1[g]);
  if (g < 2 * D * D) fc2wb[g] = f2bf(fc2_w[g]);
  if (g < n_drug * D) drugb[g] = f2bf(drug_emb[g]);
  if (g < total) out_hi[g] = x[g];
  if (g < 2 * D) bnacc[g] = 0.f;        // block 0 only
  if (g == 2 * D) *counter = 0;
  // w2 colsum: 8 independent partial accumulators -> loads fully pipelined
  if (g < D) {
    float s0=0.f,s1=0.f,s2=0.f,s3=0.f,s4=0.f,s5=0.f,s6=0.f,s7=0.f;
    #pragma unroll
    for (int j = 0; j < D; j += 8) {
      s0 += w2[(j+0)*D+g]; s1 += w2[(j+1)*D+g];
      s2 += w2[(j+2)*D+g]; s3 += w2[(j+3)*D+g];
      s4 += w2[(j+4)*D+g]; s5 += w2[(j+5)*D+g];
      s6 += w2[(j+6)*D+g]; s7 += w2[(j+7)*D+g];
    }
    w2s[g] = ((s0+s1)+(s2+s3))+((s4+s5)+(s6+s7));
  }
  // b2 sum: wave 0 of block 0, parallel shuffle reduce
  if (g < 64) {
    float v = b2[g] + b2[g + 64];
    v += __shfl_xor(v, 1);  v += __shfl_xor(v, 2);  v += __shfl_xor(v, 4);
    v += __shfl_xor(v, 8);  v += __shfl_xor(v, 16); v += __shfl_xor(v, 32);
    if (g == 0) b2sum[0] = v;
  }
}

// ---- per-drug: had = drug*rel -> z = had@w1^T + b1 (bf16 MFMA) -> sigmoid
// ---- -> score = h.w2s + b2sum -> neigh = sum score*tail (bf16 out) ----
__global__ __launch_bounds__(256, 2) void edge_kernel(
    const float* __restrict__ drug_emb, const float* __restrict__ rel_emb,
    const float* __restrict__ tail_emb, const float* __restrict__ b1,
    const int* __restrict__ dkg_rel, const int* __restrict__ dkg_tail,
    const int* __restrict__ starts, const unsigned short* __restrict__ w1b,
    const float* __restrict__ w2s, const float* __restrict__ b2sum,
    const int* __restrict__ samp, unsigned short* __restrict__ neighb) {
  const int n = blockIdx.x;
  const int tid = threadIdx.x;
  const int w = tid >> 6, lane = tid & 63;
  const int fl = lane & 15, kh = lane >> 4;
  const int g = tid >> 5, l5 = tid & 31;   // 8 groups x 32 lanes

  __shared__ __align__(16) unsigned short hadb[64][136];  // 272B row: 2-way alias only
  __shared__ float scorePart[4][64];
  __shared__ float scoreL[64];
  __shared__ int   tails[64];
  __shared__ int   relIdx[64];
  float* gpart = (float*)&hadb[0][0];  // alias: gather partials (4KB), reused after MFMA phase

  const int base = starts[n];
  const int end  = starts[n + 1];
  int ss = samp[0]; if (ss > 64) ss = 64;
  int cnt = end - base; if (cnt > ss) cnt = ss; if (cnt < 0) cnt = 0;

  if (tid < 64) {
    tails[tid]  = (tid < cnt) ? dkg_tail[base + tid] : 0;
    relIdx[tid] = (tid < cnt) ? dkg_rel[base + tid] : 0;
  }

  const f32x4 dr = *(const f32x4*)(drug_emb + (long)n * D + l5 * 4);

  // B fragments: wave w covers feature tiles {2w, 2w+1}
  bf16x8 bfr[2][4];
  float w2sr[2], b1r[2];
  #pragma unroll
  for (int jq = 0; jq < 2; ++jq) {
    int f = (w * 2 + jq) * 16 + fl;
    w2sr[jq] = w2s[f];
    b1r[jq]  = b1[f];
    #pragma unroll
    for (int kt = 0; kt < 4; ++kt)
      bfr[jq][kt] = *(const bf16x8*)(w1b + f * D + kt * 32 + kh * 8);
  }
  const float b2s = b2sum[0];

  __syncthreads();  // relIdx/tails ready

  // stage had (bf16): group g handles edges it*8+g; 32 lanes cover 128 feats
  #pragma unroll
  for (int it = 0; it < 8; ++it) {
    int e = it * 8 + g;
    int r = relIdx[e];
    f32x4 rl = *(const f32x4*)(rel_emb + (long)r * D + l5 * 4);
    f32x4 v = dr * rl;
    u16x4 pk = { f2bf(v.x), f2bf(v.y), f2bf(v.z), f2bf(v.w) };
    *(u16x4*)&hadb[e][l5 * 4] = pk;
  }

  // T14: issue tail-row loads now; consumed after the score barrier.
  f32x4 trow[8];
  #pragma unroll
  for (int it = 0; it < 8; ++it) {
    int e = it * 8 + g;
    trow[it] = *(const f32x4*)(tail_emb + (long)tails[e] * D + l5 * 4);
  }

  __syncthreads();  // hadb ready

  f32x4 acc[4][2];
  #pragma unroll
  for (int mt = 0; mt < 4; ++mt)
    #pragma unroll
    for (int jq = 0; jq < 2; ++jq)
      acc[mt][jq] = (f32x4){b1r[jq], b1r[jq], b1r[jq], b1r[jq]};

  #pragma unroll
  for (int kt = 0; kt < 4; ++kt) {
    bf16x8 af[4];
    #pragma unroll
    for (int mt = 0; mt < 4; ++mt)
      af[mt] = *(const bf16x8*)&hadb[mt * 16 + fl][kt * 32 + kh * 8];
    #pragma unroll
    for (int mt = 0; mt < 4; ++mt)
      #pragma unroll
      for (int jq = 0; jq < 2; ++jq)
        acc[mt][jq] = __builtin_amdgcn_mfma_f32_16x16x32_bf16(af[mt], bfr[jq][kt], acc[mt][jq], 0, 0, 0);
  }

  // epilogue: sigmoid, partial score over this wave's 32 features, 16-lane reduce
  #pragma unroll
  for (int mt = 0; mt < 4; ++mt) {
    #pragma unroll
    for (int r = 0; r < 4; ++r) {
      float p = 0.f;
      #pragma unroll
      for (int jq = 0; jq < 2; ++jq) {
        float hh = 1.f / (1.f + __expf(-acc[mt][jq][r]));
        p += hh * w2sr[jq];
      }
      p += __shfl_xor(p, 1);
      p += __shfl_xor(p, 2);
      p += __shfl_xor(p, 4);
      p += __shfl_xor(p, 8);
      if (fl == 0) scorePart[w][mt * 16 + kh * 4 + r] = p;
    }
  }
  __syncthreads();

  if (tid < 64) {
    float sc = scorePart[0][tid] + scorePart[1][tid] + scorePart[2][tid] + scorePart[3][tid] + b2s;
    scoreL[tid] = (tid < cnt) ? sc : 0.f;
  }
  __syncthreads();

  // weighted accumulate of prefetched tail rows
  f32x4 a = (f32x4){0.f, 0.f, 0.f, 0.f};
  #pragma unroll
  for (int it = 0; it < 8; ++it) {
    int e = it * 8 + g;
    float s = scoreL[e];            // 0 for e >= cnt
    a += trow[it] * s;
  }
  ((f32x4*)gpart)[g * 32 + l5] = a;
  __syncthreads();

  if (tid < D) {
    float s = 0.f;
    #pragma unroll
    for (int q = 0; q < 8; ++q) s += gpart[q * 128 + tid];
    neighb[(long)n * D + tid] = f2bf(s);
  }
}

// ---- fc2 (bf16 MFMA) + BN fused in ONE kernel via atomic-spin barrier.
// 32 blocks (co-resident on 256 CUs -> spin is deadlock-free). Stats go
// through device-scope atomicAdd (coherent across XCD L2s). Rows are
// normalized straight from the MFMA accumulator (no out_pre round trip).
__global__ __launch_bounds__(256, 1) void fc2bn_kernel(
    const unsigned short* __restrict__ drugb, const unsigned short* __restrict__ neighb,
    const unsigned short* __restrict__ fc2wb, const float* __restrict__ fc2_b,
    const float* __restrict__ gamma, const float* __restrict__ beta,
    float* __restrict__ bnacc, int* __restrict__ counter,
    float* __restrict__ out, int n_drug, int nblocks) {
  const int tid = threadIdx.x;
  const int w = tid >> 6, lane = tid & 63;
  const int fl = lane & 15, kh = lane >> 4;
  const int n0 = blockIdx.x * 64;

  __shared__ __align__(16) unsigned short asmem[64][264];  // 528B row stride: 2-way alias only

  #pragma unroll
  for (int it = 0; it < 8; ++it) {
    int c = it * 256 + tid;
    int row = c >> 5;
    int off = (c & 31) * 16;
    int gr = n0 + row;
    u16x8 v = (u16x8){0,0,0,0,0,0,0,0};
    if (gr < n_drug) {
      const unsigned short* src = (off < 256) ? (drugb + (long)gr * D + (off >> 1))
                                              : (neighb + (long)gr * D + ((off - 256) >> 1));
      v = *(const u16x8*)src;
    }
    *(u16x8*)((char*)&asmem[0][0] + row * 528 + off) = v;
  }

  bf16x8 bfr[2][8];
  float bjr[2];
  #pragma unroll
  for (int jq = 0; jq < 2; ++jq) {
    int f = (w * 2 + jq) * 16 + fl;
    bjr[jq] = fc2_b[f];
    #pragma unroll
    for (int kt = 0; kt < 8; ++kt)
      bfr[jq][kt] = *(const bf16x8*)(fc2wb + (long)f * 256 + kt * 32 + kh * 8);
  }
  __syncthreads();

  f32x4 acc[4][2];
  #pragma unroll
  for (int mt = 0; mt < 4; ++mt)
    #pragma unroll
    for (int jq = 0; jq < 2; ++jq)
      acc[mt][jq] = (f32x4){bjr[jq], bjr[jq], bjr[jq], bjr[jq]};

  #pragma unroll
  for (int kt = 0; kt < 8; ++kt) {
    bf16x8 af[4];
    #pragma unroll
    for (int mt = 0; mt < 4; ++mt)
      af[mt] = *(const bf16x8*)((char*)&asmem[0][0] + (mt * 16 + fl) * 528 + kt * 64 + kh * 16);
    #pragma unroll
    for (int mt = 0; mt < 4; ++mt)
      #pragma unroll
      for (int jq = 0; jq < 2; ++jq)
        acc[mt][jq] = __builtin_amdgcn_mfma_f32_16x16x32_bf16(af[mt], bfr[jq][kt], acc[mt][jq], 0, 0, 0);
  }

  // per-column partial stats -> device-scope atomic accumulate
  #pragma unroll
  for (int jq = 0; jq < 2; ++jq) {
    int j = (w * 2 + jq) * 16 + fl;
    float s = 0.f, s2 = 0.f;
    #pragma unroll
    for (int mt = 0; mt < 4; ++mt) {
      #pragma unroll
      for (int r = 0; r < 4; ++r) {
        int grow = n0 + mt * 16 + kh * 4 + r;
        float v = acc[mt][jq][r];
        if (grow < n_drug) { s += v; s2 += v * v; }
      }
    }
    s  += __shfl_xor(s, 16);  s  += __shfl_xor(s, 32);
    s2 += __shfl_xor(s2, 16); s2 += __shfl_xor(s2, 32);
    if (kh == 0) {
      atomicAdd(&bnacc[j], s);
      atomicAdd(&bnacc[D + j], s2);
    }
  }

  // spin barrier: all 32 blocks arrive, then proceed
  __syncthreads();               // drains this block's atomics (waitcnt before barrier)
  if (tid == 0) {
    __threadfence();
    atomicAdd(counter, 1);
    while (__hip_atomic_load(counter, __ATOMIC_ACQUIRE, __HIP_MEMORY_SCOPE_AGENT) < nblocks) {}
  }
  __syncthreads();

  // normalize this block's rows straight from the accumulator
  #pragma unroll
  for (int jq = 0; jq < 2; ++jq) {
    int j = (w * 2 + jq) * 16 + fl;
    float s  = __hip_atomic_load(&bnacc[j],     __ATOMIC_RELAXED, __HIP_MEMORY_SCOPE_AGENT);
    float s2 = __hip_atomic_load(&bnacc[D + j], __ATOMIC_RELAXED, __HIP_MEMORY_SCOPE_AGENT);
    float mean = s / (float)n_drug;
    float var  = s2 / (float)n_drug - mean * mean;
    float inv  = rsqrtf(var + 1e-5f);
    float sc   = inv * gamma[j];
    float sh   = beta[j] - mean * sc;
    #pragma unroll
    for (int mt = 0; mt < 4; ++mt) {
      #pragma unroll
      for (int r = 0; r < 4; ++r) {
        int grow = n0 + mt * 16 + kh * 4 + r;
        if (grow < n_drug)
          out[(long)grow * D + j] = acc[mt][jq][r] * sc + sh;
      }
    }
  }
}

extern "C" void kernel_launch(void* const* d_in, const int* in_sizes, int n_in,
                              void* d_out, int out_size, void* d_ws, size_t ws_size,
                              hipStream_t stream) {
  const float* drug_emb = (const float*)d_in[0];
  const float* rel_emb  = (const float*)d_in[1];
  const float* tail_emb = (const float*)d_in[2];
  const float* w1       = (const float*)d_in[3];
  const float* b1       = (const float*)d_in[4];
  const float* w2       = (const float*)d_in[5];
  const float* b2       = (const float*)d_in[6];
  const float* fc2_w    = (const float*)d_in[7];
  const float* fc2_b    = (const float*)d_in[8];
  const float* gamma    = (const float*)d_in[9];
  const float* beta     = (const float*)d_in[10];
  const float* x        = (const float*)d_in[11];
  const int*   dkg_head = (const int*)d_in[12];
  const int*   dkg_rel  = (const int*)d_in[13];
  const int*   dkg_tail = (const int*)d_in[14];
  const int*   samp     = (const int*)d_in[15];

  const int n_drug = in_sizes[0] / D;   // 2000
  const int E      = in_sizes[12];      // 500000
  float* out = (float*)d_out;
  const int total = out_size / 2;       // 256000

  // workspace layout
  char* ws = (char*)d_ws;
  int*            starts  = (int*)(ws + 0);                     // 8004 B
  unsigned short* w1b     = (unsigned short*)(ws + 8192);       // 32768 B
  float*          w2s     = (float*)(ws + 40960);               // 512 B
  float*          b2sum   = (float*)(ws + 41472);               // 4 B
  unsigned short* fc2wb   = (unsigned short*)(ws + 49152);      // 65536 B
  unsigned short* drugb   = (unsigned short*)(ws + 131072);     // 512000 B
  unsigned short* neighb  = (unsigned short*)(ws + 655360);     // 512000 B
  float*          bnacc   = (float*)(ws + 1179648);             // 1024 B
  int*            counter = (int*)(ws + 1180672);               // 4 B

  const int nbf = (n_drug + 63) / 64;   // 32 fc2bn blocks

  hipLaunchKernelGGL(prep_kernel, dim3((E + 256) / 256), dim3(256), 0, stream,
                     w1, w2, b2, drug_emb, fc2_w, x, dkg_head,
                     w1b, drugb, fc2wb, starts, w2s, b2sum, out + total,
                     bnacc, counter, E, n_drug, total);
  hipLaunchKernelGGL(edge_kernel, dim3(n_drug), dim3(256), 0, stream,
                     drug_emb, rel_emb, tail_emb, b1, dkg_rel, dkg_tail,
                     starts, w1b, w2s, b2sum, samp, neighb);
  hipLaunchKernelGGL(fc2bn_kernel, dim3(nbf), dim3(256), 0, stream,
                     drugb, neighb, fc2wb, fc2_b, gamma, beta,
                     bnacc, counter, out, n_drug, nbf);
}